// Round 1
// baseline (1516.523 us; speedup 1.0000x reference)
//
#include <hip/hip_runtime.h>
#include <hip/hip_bf16.h>
#include <stdint.h>

#define NN   16384
#define FIN  512
#define FHID 256

using f32x4  = __attribute__((ext_vector_type(4))) float;
using bf16x8 = __attribute__((ext_vector_type(8))) __bf16;

// float -> bf16 bits, round-to-nearest-even (inputs are finite)
__device__ __forceinline__ uint16_t f2b(float f) {
  union { float f; uint32_t u; } a; a.f = f;
  uint32_t r = a.u + 0x7fffu + ((a.u >> 16) & 1u);
  return (uint16_t)(r >> 16);
}

// async global->LDS, 16B per lane; lds must be wave-uniform (HW does base + lane*16)
__device__ __forceinline__ void async_lds16(void* lds, const void* g) {
  __builtin_amdgcn_global_load_lds((const __attribute__((address_space(1))) void*)g,
                                   (__attribute__((address_space(3))) void*)lds,
                                   16, 0, 0);
}

// 8 fp32 -> 8 bf16 packed, one ds_write_b128
__device__ __forceinline__ void cvt_store8(void* dst, float4 a, float4 b) {
  union { uint16_t u[8]; int4 v; } p;
  p.u[0] = f2b(a.x); p.u[1] = f2b(a.y); p.u[2] = f2b(a.z); p.u[3] = f2b(a.w);
  p.u[4] = f2b(b.x); p.u[5] = f2b(b.y); p.u[6] = f2b(b.z); p.u[7] = f2b(b.w);
  *(int4*)dst = p.v;
}

// ---------------- kernel 0: W (512x256 f32) -> WT (256x512 bf16) ----------------
__global__ void transpose_w(const float* __restrict__ W, uint16_t* __restrict__ WT) {
  int t = blockIdx.x * 256 + threadIdx.x;   // 131072 threads
  int k = t >> 8;
  int h = t & 255;
  WT[h * FIN + k] = f2b(W[t]);
}

// ---------------- kernel 1: supportT[h][n] = (x @ W)^T, bf16 ----------------
// BM=64 (n rows of x), BN=256 (=FHID), BK=64, 8 K-iters. 256 blocks x 256 thr.
__global__ __launch_bounds__(256, 1) void gemm_xw(
    const float* __restrict__ x, const uint16_t* __restrict__ WT,
    uint16_t* __restrict__ supT)
{
  constexpr int BK = 64;
  constexpr int ITERS = FIN / BK; // 8
  __shared__ alignas(16) char smem[81920];
  char* const bufB = smem;            // 2 x 32768 : [h(256)][128B swizzled]
  char* const bufA = smem + 65536;    // 2 x 8192  : [m(64)][128B swizzled]

  const int tid  = threadIdx.x;
  const int lane = tid & 63;
  const int wave = tid >> 6;
  const int g    = lane >> 4;
  const int l15  = lane & 15;
  const int rowBase = blockIdx.x * 64;

  const int am  = tid >> 3;
  const int akg = tid & 7;
  const float* ap0 = x + (size_t)(rowBase + am) * FIN + akg * 8;
  const float* ap1 = ap0 + (size_t)32 * FIN;
  const int awoff = am * 128 + ((akg ^ (am & 7)) << 4);

  const uint16_t* bgp[8];
  int bwoff[8];
#pragma unroll
  for (int i = 0; i < 8; ++i) {
    int o = i * 4096 + wave * 1024 + lane * 16;
    int n = o >> 7;                       // h row 0..255
    int c = ((o >> 4) & 7) ^ (n & 7);     // logical 16B k-chunk
    bgp[i] = WT + (size_t)n * FIN + c * 8;
    bwoff[i] = i * 4096 + wave * 1024;
  }

  int aoff[2], boff[2];
#pragma unroll
  for (int s = 0; s < 2; ++s) {
    int sw = ((s * 4 + g) ^ (l15 & 7)) << 4;
    aoff[s] = l15 * 128 + sw;
    boff[s] = (wave * 64 + l15) * 128 + sw;
  }

  f32x4 acc[4][4] = {};

  { // prologue: stage k=0 into buf 0
    const float4* q0 = (const float4*)ap0;
    const float4* q1 = (const float4*)ap1;
    float4 a0 = q0[0], a1 = q0[1], b0 = q1[0], b1 = q1[1];
#pragma unroll
    for (int i = 0; i < 8; ++i) async_lds16(bufB + bwoff[i], bgp[i]);
    cvt_store8(bufA + awoff, a0, a1);
    cvt_store8(bufA + awoff + 4096, b0, b1);
    ap0 += BK; ap1 += BK;
#pragma unroll
    for (int i = 0; i < 8; ++i) bgp[i] += BK;
  }
  __syncthreads();

  for (int k = 0; k < ITERS; ++k) {
    const int cur = k & 1, nxt = cur ^ 1;
    const bool pf = (k + 1 < ITERS);
    float4 a0, a1, b0, b1;
    if (pf) {
      const float4* q0 = (const float4*)ap0;
      const float4* q1 = (const float4*)ap1;
      a0 = q0[0]; a1 = q0[1]; b0 = q1[0]; b1 = q1[1];
#pragma unroll
      for (int i = 0; i < 8; ++i) async_lds16(bufB + nxt * 32768 + bwoff[i], bgp[i]);
      ap0 += BK; ap1 += BK;
#pragma unroll
      for (int i = 0; i < 8; ++i) bgp[i] += BK;
    }
    char* A = bufA + cur * 8192;
    char* B = bufB + cur * 32768;
#pragma unroll
    for (int s = 0; s < 2; ++s) {
      bf16x8 af[4], bfr[4];
#pragma unroll
      for (int mt = 0; mt < 4; ++mt) af[mt]  = *(const bf16x8*)(A + aoff[s] + mt * 2048);
#pragma unroll
      for (int nt = 0; nt < 4; ++nt) bfr[nt] = *(const bf16x8*)(B + boff[s] + nt * 2048);
#pragma unroll
      for (int mt = 0; mt < 4; ++mt)
#pragma unroll
        for (int nt = 0; nt < 4; ++nt)
          acc[mt][nt] = __builtin_amdgcn_mfma_f32_16x16x32_bf16(af[mt], bfr[nt], acc[mt][nt], 0, 0, 0);
    }
    if (pf) {
      cvt_store8(bufA + nxt * 8192 + awoff, a0, a1);
      cvt_store8(bufA + nxt * 8192 + awoff + 4096, b0, b1);
    }
    __syncthreads();
  }

  // epilogue: store transposed bf16. acc regs r = consecutive n rows at fixed h.
#pragma unroll
  for (int mt = 0; mt < 4; ++mt)
#pragma unroll
    for (int nt = 0; nt < 4; ++nt) {
      int h  = wave * 64 + nt * 16 + l15;
      int n0 = rowBase + mt * 16 + g * 4;
      union { uint16_t u[4]; uint2 v; } p;
#pragma unroll
      for (int r = 0; r < 4; ++r) p.u[r] = f2b(acc[mt][nt][r]);
      *(uint2*)(supT + (size_t)h * NN + n0) = p.v;
    }
}

// ---------------- kernel 2: embed1 = adj @ support + b ; logp = log_softmax ----------------
// BM=64, BN=256, BK=64, 256 K-iters. 256 blocks x 256 thr (1 block/CU).
__global__ __launch_bounds__(256, 1) void gemm_adj(
    const float* __restrict__ adj, const uint16_t* __restrict__ supT,
    const float* __restrict__ bias, float* __restrict__ out_logp,
    float* __restrict__ out_emb)
{
  constexpr int BK = 64;
  constexpr int ITERS = NN / BK; // 256
  __shared__ alignas(16) char smem[83968];
  char* const bufB = smem;                      // 2 x 32768
  char* const bufA = smem + 65536;              // 2 x 8192
  float* const wred = (float*)(smem + 81920);   // wmax[4][64] + wsum[4][64]

  const int tid  = threadIdx.x;
  const int lane = tid & 63;
  const int wave = tid >> 6;
  const int g    = lane >> 4;
  const int l15  = lane & 15;
  const int rowBase = blockIdx.x * 64;

  const int am  = tid >> 3;
  const int akg = tid & 7;
  const float* ap0 = adj + (size_t)(rowBase + am) * NN + akg * 8;
  const float* ap1 = ap0 + (size_t)32 * NN;
  const int awoff = am * 128 + ((akg ^ (am & 7)) << 4);

  const uint16_t* bgp[8];
  int bwoff[8];
#pragma unroll
  for (int i = 0; i < 8; ++i) {
    int o = i * 4096 + wave * 1024 + lane * 16;
    int n = o >> 7;
    int c = ((o >> 4) & 7) ^ (n & 7);
    bgp[i] = supT + (size_t)n * NN + c * 8;
    bwoff[i] = i * 4096 + wave * 1024;
  }

  int aoff[2], boff[2];
#pragma unroll
  for (int s = 0; s < 2; ++s) {
    int sw = ((s * 4 + g) ^ (l15 & 7)) << 4;
    aoff[s] = l15 * 128 + sw;
    boff[s] = (wave * 64 + l15) * 128 + sw;
  }

  f32x4 acc[4][4] = {};

  { // prologue
    const float4* q0 = (const float4*)ap0;
    const float4* q1 = (const float4*)ap1;
    float4 a0 = q0[0], a1 = q0[1], b0 = q1[0], b1 = q1[1];
#pragma unroll
    for (int i = 0; i < 8; ++i) async_lds16(bufB + bwoff[i], bgp[i]);
    cvt_store8(bufA + awoff, a0, a1);
    cvt_store8(bufA + awoff + 4096, b0, b1);
    ap0 += BK; ap1 += BK;
#pragma unroll
    for (int i = 0; i < 8; ++i) bgp[i] += BK;
  }
  __syncthreads();

  for (int k = 0; k < ITERS; ++k) {
    const int cur = k & 1, nxt = cur ^ 1;
    const bool pf = (k + 1 < ITERS);
    float4 a0, a1, b0, b1;
    if (pf) {
      const float4* q0 = (const float4*)ap0;
      const float4* q1 = (const float4*)ap1;
      a0 = q0[0]; a1 = q0[1]; b0 = q1[0]; b1 = q1[1];
#pragma unroll
      for (int i = 0; i < 8; ++i) async_lds16(bufB + nxt * 32768 + bwoff[i], bgp[i]);
      ap0 += BK; ap1 += BK;
#pragma unroll
      for (int i = 0; i < 8; ++i) bgp[i] += BK;
    }
    char* A = bufA + cur * 8192;
    char* B = bufB + cur * 32768;
#pragma unroll
    for (int s = 0; s < 2; ++s) {
      bf16x8 af[4], bfr[4];
#pragma unroll
      for (int mt = 0; mt < 4; ++mt) af[mt]  = *(const bf16x8*)(A + aoff[s] + mt * 2048);
#pragma unroll
      for (int nt = 0; nt < 4; ++nt) bfr[nt] = *(const bf16x8*)(B + boff[s] + nt * 2048);
#pragma unroll
      for (int mt = 0; mt < 4; ++mt)
#pragma unroll
        for (int nt = 0; nt < 4; ++nt)
          acc[mt][nt] = __builtin_amdgcn_mfma_f32_16x16x32_bf16(af[mt], bfr[nt], acc[mt][nt], 0, 0, 0);
    }
    if (pf) {
      cvt_store8(bufA + nxt * 8192 + awoff, a0, a1);
      cvt_store8(bufA + nxt * 8192 + awoff + 4096, b0, b1);
    }
    __syncthreads();
  }

  // ---- epilogue: +bias, store embed1, fused log_softmax over 256 cols ----
  float bv[4];
#pragma unroll
  for (int nt = 0; nt < 4; ++nt) bv[nt] = bias[wave * 64 + nt * 16 + l15];
#pragma unroll
  for (int mt = 0; mt < 4; ++mt)
#pragma unroll
    for (int nt = 0; nt < 4; ++nt)
#pragma unroll
      for (int r = 0; r < 4; ++r) acc[mt][nt][r] += bv[nt];

  float* oute = out_emb + (size_t)rowBase * FHID;
#pragma unroll
  for (int mt = 0; mt < 4; ++mt)
#pragma unroll
    for (int nt = 0; nt < 4; ++nt) {
      int col = wave * 64 + nt * 16 + l15;
#pragma unroll
      for (int r = 0; r < 4; ++r) {
        int row = mt * 16 + g * 4 + r;
        oute[row * FHID + col] = acc[mt][nt][r];
      }
    }

  // per-lane: 16 rows (mt,g,r), 4 cols each (nt). Reduce over nt, then 16-lane group, then 4 waves.
  float rmax[16];
#pragma unroll
  for (int mt = 0; mt < 4; ++mt)
#pragma unroll
    for (int r = 0; r < 4; ++r) {
      float m = acc[mt][0][r];
#pragma unroll
      for (int nt = 1; nt < 4; ++nt) m = fmaxf(m, acc[mt][nt][r]);
      rmax[mt * 4 + r] = m;
    }
#pragma unroll
  for (int off = 1; off <= 8; off <<= 1)
#pragma unroll
    for (int i = 0; i < 16; ++i) rmax[i] = fmaxf(rmax[i], __shfl_xor(rmax[i], off, 64));

  float* wmax = wred;
  float* wsum = wred + 256;
  if (l15 == 0) {
#pragma unroll
    for (int mt = 0; mt < 4; ++mt)
#pragma unroll
      for (int r = 0; r < 4; ++r) wmax[wave * 64 + mt * 16 + g * 4 + r] = rmax[mt * 4 + r];
  }
  __syncthreads();

  float fmx[16];
#pragma unroll
  for (int mt = 0; mt < 4; ++mt)
#pragma unroll
    for (int r = 0; r < 4; ++r) {
      int row = mt * 16 + g * 4 + r;
      fmx[mt * 4 + r] = fmaxf(fmaxf(wmax[row], wmax[64 + row]), fmaxf(wmax[128 + row], wmax[192 + row]));
    }

  float rsum[16];
#pragma unroll
  for (int i = 0; i < 16; ++i) rsum[i] = 0.f;
#pragma unroll
  for (int mt = 0; mt < 4; ++mt)
#pragma unroll
    for (int nt = 0; nt < 4; ++nt)
#pragma unroll
      for (int r = 0; r < 4; ++r)
        rsum[mt * 4 + r] += __expf(acc[mt][nt][r] - fmx[mt * 4 + r]);
#pragma unroll
  for (int off = 1; off <= 8; off <<= 1)
#pragma unroll
    for (int i = 0; i < 16; ++i) rsum[i] += __shfl_xor(rsum[i], off, 64);

  if (l15 == 0) {
#pragma unroll
    for (int mt = 0; mt < 4; ++mt)
#pragma unroll
      for (int r = 0; r < 4; ++r) wsum[wave * 64 + mt * 16 + g * 4 + r] = rsum[mt * 4 + r];
  }
  __syncthreads();

  float lz[16];
#pragma unroll
  for (int mt = 0; mt < 4; ++mt)
#pragma unroll
    for (int r = 0; r < 4; ++r) {
      int row = mt * 16 + g * 4 + r;
      float s = wsum[row] + wsum[64 + row] + wsum[128 + row] + wsum[192 + row];
      lz[mt * 4 + r] = fmx[mt * 4 + r] + __logf(s);
    }

  float* outl = out_logp + (size_t)rowBase * FHID;
#pragma unroll
  for (int mt = 0; mt < 4; ++mt)
#pragma unroll
    for (int nt = 0; nt < 4; ++nt) {
      int col = wave * 64 + nt * 16 + l15;
#pragma unroll
      for (int r = 0; r < 4; ++r) {
        int row = mt * 16 + g * 4 + r;
        outl[row * FHID + col] = acc[mt][nt][r] - lz[mt * 4 + r];
      }
    }
}

extern "C" void kernel_launch(void* const* d_in, const int* in_sizes, int n_in,
                              void* d_out, int out_size, void* d_ws, size_t ws_size,
                              hipStream_t stream) {
  (void)in_sizes; (void)n_in; (void)out_size; (void)ws_size;
  const float* x   = (const float*)d_in[0];
  const float* adj = (const float*)d_in[1];
  const float* W   = (const float*)d_in[2];
  const float* b   = (const float*)d_in[3];
  float* out_logp = (float*)d_out;
  float* out_emb  = out_logp + (size_t)NN * FHID;

  uint16_t* supT = (uint16_t*)d_ws;                                   // 256 x 16384 bf16 (8 MB)
  uint16_t* WT   = (uint16_t*)((char*)d_ws + (size_t)FHID * NN * 2);  // 256 x 512 bf16 (256 KB)

  transpose_w<<<dim3((FIN * FHID) / 256), dim3(256), 0, stream>>>(W, WT);
  gemm_xw<<<dim3(NN / 64), dim3(256), 0, stream>>>(x, WT, supT);
  gemm_adj<<<dim3(NN / 64), dim3(256), 0, stream>>>(adj, supT, b, out_logp, out_emb);
}